// Round 1
// baseline (1540.481 us; speedup 1.0000x reference)
//
#include <hip/hip_runtime.h>
#include <hip/hip_bf16.h>

// Problem dims (fixed by reference): x[B*S=8192, E=2048], w1/w2[H=8192, E], w3[E, H]
#define M_ROWS 8192
#define E_DIM  2048
#define H_DIM  8192

typedef __attribute__((ext_vector_type(8))) short bf16x8;
typedef __attribute__((ext_vector_type(4))) float f32x4;
typedef __attribute__((ext_vector_type(4))) unsigned int uint4v;

__device__ __forceinline__ unsigned short f2bf_rne(float x) {
  unsigned u = __builtin_bit_cast(unsigned, x);
  u += 0x7FFFu + ((u >> 16) & 1u);
  return (unsigned short)(u >> 16);
}

// ---------------- fp32 -> bf16 conversion (memory-bound, vectorized) ----------------
__global__ __launch_bounds__(256) void cvt_f32_bf16(const float* __restrict__ in,
                                                    unsigned short* __restrict__ out,
                                                    int n8) {
  int i = blockIdx.x * blockDim.x + threadIdx.x;
  if (i >= n8) return;
  const float4* p = (const float4*)(in + (size_t)i * 8);
  float4 a = p[0];
  float4 b = p[1];
  union { unsigned short us[8]; uint4v v; } r;
  r.us[0] = f2bf_rne(a.x); r.us[1] = f2bf_rne(a.y);
  r.us[2] = f2bf_rne(a.z); r.us[3] = f2bf_rne(a.w);
  r.us[4] = f2bf_rne(b.x); r.us[5] = f2bf_rne(b.y);
  r.us[6] = f2bf_rne(b.z); r.us[7] = f2bf_rne(b.w);
  *(uint4v*)(out + (size_t)i * 8) = r.v;
}

// ---------------- async global -> LDS, 16B per lane ----------------
__device__ __forceinline__ void gld_lds16(const unsigned short* g, unsigned short* l) {
  __builtin_amdgcn_global_load_lds(
      (const __attribute__((address_space(1))) unsigned int*)g,
      (__attribute__((address_space(3))) unsigned int*)l, 16, 0, 0);
}

// ---------------- GEMM: C[M,N] = A[M,K] * B[N,K]^T (row-major, K contiguous) ----------------
// m97 structure: 128x128 tile, BK=64, 256 threads (4 waves, 2x2), each wave 64x64 out
// (4x4 grid of 16x16 frags), mfma_f32_16x16x32_bf16.
// DUAL=1: two B operands (w1,w2); epilogue writes bf16 silu(acc1)*acc2.
// DUAL=0: one B; epilogue writes fp32 acc1.
template <int DUAL>
__global__ __launch_bounds__(256)
void gemm_bt(const unsigned short* __restrict__ A,
             const unsigned short* __restrict__ B1,
             const unsigned short* __restrict__ B2,
             void* __restrict__ Cout,
             int M, int N, int K) {
  __shared__ unsigned short lA[128 * 64];
  __shared__ unsigned short lB1[128 * 64];
  __shared__ unsigned short lB2[DUAL ? 128 * 64 : 8];

  const int tid = threadIdx.x;
  const int lane = tid & 63;
  const int wave = tid >> 6;
  const int wr = wave >> 1, wc = wave & 1;
  const int lr = lane & 15, lk = lane >> 4;

  const int brow = blockIdx.y, bcol = blockIdx.x;

  f32x4 acc1[4][4] = {};
  f32x4 acc2[4][4] = {};  // DCE'd when !DUAL

  const unsigned short* Ag  = A  + (size_t)brow * 128 * K;
  const unsigned short* B1g = B1 + (size_t)bcol * 128 * K;
  const unsigned short* B2g = DUAL ? (B2 + (size_t)bcol * 128 * K) : B1;

  const int e0 = tid * 8;  // element offset of this thread's 16B chunk (call 0)

  for (int k0 = 0; k0 < K; k0 += 64) {
#pragma unroll
    for (int c = 0; c < 4; ++c) {
      int e = c * 2048 + e0;
      int r = e >> 6, cl = e & 63;
      gld_lds16(Ag + (size_t)r * K + k0 + cl, &lA[e]);
    }
#pragma unroll
    for (int c = 0; c < 4; ++c) {
      int e = c * 2048 + e0;
      int r = e >> 6, cl = e & 63;
      gld_lds16(B1g + (size_t)r * K + k0 + cl, &lB1[e]);
    }
    if constexpr (DUAL) {
#pragma unroll
      for (int c = 0; c < 4; ++c) {
        int e = c * 2048 + e0;
        int r = e >> 6, cl = e & 63;
        gld_lds16(B2g + (size_t)r * K + k0 + cl, &lB2[e]);
      }
    }
    __syncthreads();  // compiler emits vmcnt(0) drain before s_barrier

#pragma unroll
    for (int kk = 0; kk < 64; kk += 32) {
      bf16x8 af[4], bf1[4], bf2[4];
      const int ko = kk + lk * 8;
#pragma unroll
      for (int m = 0; m < 4; ++m)
        af[m] = *(const bf16x8*)&lA[(wr * 64 + m * 16 + lr) * 64 + ko];
#pragma unroll
      for (int n = 0; n < 4; ++n)
        bf1[n] = *(const bf16x8*)&lB1[(wc * 64 + n * 16 + lr) * 64 + ko];
      if constexpr (DUAL) {
#pragma unroll
        for (int n = 0; n < 4; ++n)
          bf2[n] = *(const bf16x8*)&lB2[(wc * 64 + n * 16 + lr) * 64 + ko];
      }
#pragma unroll
      for (int m = 0; m < 4; ++m) {
#pragma unroll
        for (int n = 0; n < 4; ++n) {
          acc1[m][n] = __builtin_amdgcn_mfma_f32_16x16x32_bf16(af[m], bf1[n], acc1[m][n], 0, 0, 0);
          if constexpr (DUAL)
            acc2[m][n] = __builtin_amdgcn_mfma_f32_16x16x32_bf16(af[m], bf2[n], acc2[m][n], 0, 0, 0);
        }
      }
    }
    __syncthreads();
  }

  // Epilogue. C/D frag layout (measured, m89/m91): col = lane&15, row = (lane>>4)*4 + j
  const int row0 = brow * 128 + wr * 64 + lk * 4;
  const int col0 = bcol * 128 + wc * 64 + lr;
#pragma unroll
  for (int m = 0; m < 4; ++m) {
#pragma unroll
    for (int n = 0; n < 4; ++n) {
#pragma unroll
      for (int j = 0; j < 4; ++j) {
        int r = row0 + m * 16 + j;
        int cN = col0 + n * 16;
        if constexpr (DUAL) {
          float g = acc1[m][n][j];
          float u = acc2[m][n][j];
          float s = g / (1.0f + __expf(-g));  // silu
          ((unsigned short*)Cout)[(size_t)r * N + cN] = f2bf_rne(s * u);
        } else {
          ((float*)Cout)[(size_t)r * N + cN] = acc1[m][n][j];
        }
      }
    }
  }
}

extern "C" void kernel_launch(void* const* d_in, const int* in_sizes, int n_in,
                              void* d_out, int out_size, void* d_ws, size_t ws_size,
                              hipStream_t stream) {
  const float* x  = (const float*)d_in[0];
  const float* w1 = (const float*)d_in[1];
  const float* w2 = (const float*)d_in[2];
  const float* w3 = (const float*)d_in[3];
  float* out = (float*)d_out;

  const int M = M_ROWS, E = E_DIM, H = H_DIM;

  // ws layout (bytes): [0,32M) x_bf16 (later reused for w3_bf16)
  //                    [32M,64M) w1_bf16 | [64M,96M) w2_bf16 | [96M,224M) h_bf16
  unsigned short* xb  = (unsigned short*)d_ws;
  unsigned short* w1b = xb + (size_t)M * E;
  unsigned short* w2b = w1b + (size_t)H * E;
  unsigned short* hb  = w2b + (size_t)H * E;
  unsigned short* w3b = xb;  // safe: GEMM1 (reader of xb) is ordered before w3 cvt on stream

  const int n8 = (M * E) / 8;  // == (H*E)/8 == 2097152
  cvt_f32_bf16<<<dim3(n8 / 256), 256, 0, stream>>>(x, xb, n8);
  cvt_f32_bf16<<<dim3(n8 / 256), 256, 0, stream>>>(w1, w1b, n8);
  cvt_f32_bf16<<<dim3(n8 / 256), 256, 0, stream>>>(w2, w2b, n8);

  // h = silu(x w1^T) * (x w2^T)  -> bf16 [M, H]
  gemm_bt<1><<<dim3(H / 128, M / 128), 256, 0, stream>>>(xb, w1b, w2b, hb, M, H, E);

  cvt_f32_bf16<<<dim3(n8 / 256), 256, 0, stream>>>(w3, w3b, n8);

  // out = h w3^T -> fp32 [M, E]
  gemm_bt<0><<<dim3(E / 128, M / 128), 256, 0, stream>>>(hb, w3b, nullptr, out, M, E, H);
}

// Round 2
// 1241.826 us; speedup vs baseline: 1.2405x; 1.2405x over previous
//
#include <hip/hip_runtime.h>
#include <hip/hip_bf16.h>

// Problem dims (fixed by reference): x[B*S=8192, E=2048], w1/w2[H=8192, E], w3[E, H]
#define M_ROWS 8192
#define E_DIM  2048
#define H_DIM  8192

typedef __attribute__((ext_vector_type(8))) short bf16x8;
typedef __attribute__((ext_vector_type(4))) float f32x4;
typedef __attribute__((ext_vector_type(4))) unsigned int uint4v;

__device__ __forceinline__ unsigned short f2bf_rne(float x) {
  unsigned u = __builtin_bit_cast(unsigned, x);
  u += 0x7FFFu + ((u >> 16) & 1u);
  return (unsigned short)(u >> 16);
}

__device__ __forceinline__ float bf2f(unsigned short b) {
  unsigned u = ((unsigned)b) << 16;
  return __builtin_bit_cast(float, u);
}

// ---------------- fp32 -> bf16 conversion (memory-bound, vectorized) ----------------
__global__ __launch_bounds__(256) void cvt_f32_bf16(const float* __restrict__ in,
                                                    unsigned short* __restrict__ out,
                                                    int n8) {
  int i = blockIdx.x * blockDim.x + threadIdx.x;
  if (i >= n8) return;
  const float4* p = (const float4*)(in + (size_t)i * 8);
  float4 a = p[0];
  float4 b = p[1];
  union { unsigned short us[8]; uint4v v; } r;
  r.us[0] = f2bf_rne(a.x); r.us[1] = f2bf_rne(a.y);
  r.us[2] = f2bf_rne(a.z); r.us[3] = f2bf_rne(a.w);
  r.us[4] = f2bf_rne(b.x); r.us[5] = f2bf_rne(b.y);
  r.us[6] = f2bf_rne(b.z); r.us[7] = f2bf_rne(b.w);
  *(uint4v*)(out + (size_t)i * 8) = r.v;
}

// ---------------- async global -> LDS, 16B per lane ----------------
__device__ __forceinline__ void gld_lds16(const unsigned short* g, unsigned short* l) {
  __builtin_amdgcn_global_load_lds(
      (const __attribute__((address_space(1))) unsigned int*)g,
      (__attribute__((address_space(3))) unsigned int*)l, 16, 0, 0);
}

// ---------------- GEMM: C[M,N] = A[M,K] * B[N,K]^T (row-major, K contiguous) ----------------
// m97 structure: 128x128 tile, BK=64, 256 threads (4 waves, 2x2), each wave 64x64 out
// (4x4 grid of 16x16 frags), mfma_f32_16x16x32_bf16. Bijective XCD swizzle on block id.
// EPI=0: store fp32 acc (down-proj -> d_out)
// EPI=1: store bf16 acc (gate raw)
// EPI=2: load gate bf16 at same index, store bf16 silu(gate)*acc (h, in-place over gate ok)
template <int EPI>
__global__ __launch_bounds__(256)
void gemm_bt(const unsigned short* __restrict__ A,
             const unsigned short* __restrict__ B,
             const unsigned short* __restrict__ Gate,
             void* __restrict__ Cout,
             int M, int N, int K) {
  __shared__ unsigned short lA[128 * 64];
  __shared__ unsigned short lB[128 * 64];

  const int tid = threadIdx.x;
  const int lane = tid & 63;
  const int wave = tid >> 6;
  const int wr = wave >> 1, wc = wave & 1;
  const int lr = lane & 15, lk = lane >> 4;

  // XCD-aware bijective swizzle (nwg % 8 == 0 for all our launches)
  const int nwg = gridDim.x * gridDim.y;
  const int wg = blockIdx.y * gridDim.x + blockIdx.x;
  const int swz = (wg & 7) * (nwg >> 3) + (wg >> 3);
  const int bcol = swz % gridDim.x;
  const int brow = swz / gridDim.x;

  f32x4 acc[4][4] = {};

  const unsigned short* Ag = A + (size_t)brow * 128 * K;
  const unsigned short* Bg = B + (size_t)bcol * 128 * K;

  const int e0 = tid * 8;  // element offset of this thread's 16B staging chunk

  for (int k0 = 0; k0 < K; k0 += 64) {
#pragma unroll
    for (int c = 0; c < 4; ++c) {
      int e = c * 2048 + e0;
      int r = e >> 6, cl = e & 63;
      gld_lds16(Ag + (size_t)r * K + k0 + cl, &lA[e]);
    }
#pragma unroll
    for (int c = 0; c < 4; ++c) {
      int e = c * 2048 + e0;
      int r = e >> 6, cl = e & 63;
      gld_lds16(Bg + (size_t)r * K + k0 + cl, &lB[e]);
    }
    __syncthreads();  // compiler emits vmcnt(0) drain before s_barrier

#pragma unroll
    for (int kk = 0; kk < 64; kk += 32) {
      bf16x8 af[4], bf[4];
      const int ko = kk + lk * 8;
#pragma unroll
      for (int m = 0; m < 4; ++m)
        af[m] = *(const bf16x8*)&lA[(wr * 64 + m * 16 + lr) * 64 + ko];
#pragma unroll
      for (int n = 0; n < 4; ++n)
        bf[n] = *(const bf16x8*)&lB[(wc * 64 + n * 16 + lr) * 64 + ko];
#pragma unroll
      for (int m = 0; m < 4; ++m)
#pragma unroll
        for (int n = 0; n < 4; ++n)
          acc[m][n] = __builtin_amdgcn_mfma_f32_16x16x32_bf16(af[m], bf[n], acc[m][n], 0, 0, 0);
    }
    __syncthreads();
  }

  // Epilogue. C/D frag layout (measured, m89/m91): col = lane&15, row = (lane>>4)*4 + j
  const int row0 = brow * 128 + wr * 64 + lk * 4;
  const int col0 = bcol * 128 + wc * 64 + lr;
#pragma unroll
  for (int m = 0; m < 4; ++m) {
#pragma unroll
    for (int n = 0; n < 4; ++n) {
#pragma unroll
      for (int j = 0; j < 4; ++j) {
        size_t idx = (size_t)(row0 + m * 16 + j) * N + (col0 + n * 16);
        float v = acc[m][n][j];
        if constexpr (EPI == 0) {
          ((float*)Cout)[idx] = v;
        } else if constexpr (EPI == 1) {
          ((unsigned short*)Cout)[idx] = f2bf_rne(v);
        } else {
          float g = bf2f(Gate[idx]);
          float s = g / (1.0f + __expf(-g));  // silu
          ((unsigned short*)Cout)[idx] = f2bf_rne(s * v);
        }
      }
    }
  }
}

extern "C" void kernel_launch(void* const* d_in, const int* in_sizes, int n_in,
                              void* d_out, int out_size, void* d_ws, size_t ws_size,
                              hipStream_t stream) {
  const float* x  = (const float*)d_in[0];
  const float* w1 = (const float*)d_in[1];
  const float* w2 = (const float*)d_in[2];
  const float* w3 = (const float*)d_in[3];
  float* out = (float*)d_out;

  const int M = M_ROWS, E = E_DIM, H = H_DIM;

  // ws layout (bf16 elements):
  //   [0, 32MB)   xb   (reused for w3b after up-GEMM)
  //   [32, 64MB)  w1b  (reused for w2b after gate-GEMM)
  //   [64, 192MB) gate -> h (silu-mul written in-place)
  unsigned short* xb  = (unsigned short*)d_ws;
  unsigned short* w1b = xb + (size_t)M * E;
  unsigned short* gb  = w1b + (size_t)H * E;
  unsigned short* w2b = w1b;  // safe: cvt(w2) is stream-ordered after gate-GEMM reads w1b
  unsigned short* w3b = xb;   // safe: cvt(w3) is stream-ordered after up-GEMM reads xb

  const int n8 = (M * E) / 8;  // == (H*E)/8 == (E*H)/8 == 2097152
  cvt_f32_bf16<<<dim3(n8 / 256), 256, 0, stream>>>(x, xb, n8);
  cvt_f32_bf16<<<dim3(n8 / 256), 256, 0, stream>>>(w1, w1b, n8);

  // gate = x w1^T  -> bf16 [M, H]
  gemm_bt<1><<<dim3(H / 128, M / 128), 256, 0, stream>>>(xb, w1b, nullptr, gb, M, H, E);

  cvt_f32_bf16<<<dim3(n8 / 256), 256, 0, stream>>>(w2, w2b, n8);

  // h = silu(gate) * (x w2^T) -> bf16 [M, H], in-place over gate
  gemm_bt<2><<<dim3(H / 128, M / 128), 256, 0, stream>>>(xb, w2b, gb, gb, M, H, E);

  cvt_f32_bf16<<<dim3(n8 / 256), 256, 0, stream>>>(w3, w3b, n8);

  // out = h w3^T -> fp32 [M, E]
  gemm_bt<0><<<dim3(E / 128, M / 128), 256, 0, stream>>>(gb, w3b, nullptr, out, M, E, H);
}